// Round 1
// baseline (727.590 us; speedup 1.0000x reference)
//
#include <hip/hip_runtime.h>
#include <cstdint>
#include <cmath>

#define F_INN 128
#define HIDD  128
#define NCLS  40

// ---------------- degree / norm ----------------

__global__ __launch_bounds__(256) void k_deg(const int* __restrict__ ei, int* __restrict__ deg, int E) {
    int e = blockIdx.x * 256 + threadIdx.x;
    if (e < E) atomicAdd(&deg[ei[E + e]], 1);   // dst = ei[1][e]
}

__global__ __launch_bounds__(256) void k_dinv(const int* __restrict__ deg, float* __restrict__ dinv, int n) {
    int i = blockIdx.x * 256 + threadIdx.x;
    if (i < n) dinv[i] = rsqrtf((float)(deg[i] + 1));  // +1 self loop
}

// ---------------- exclusive scan (rowptr) ----------------

#define SCAN_T 256
#define SCAN_E 1024

__global__ __launch_bounds__(SCAN_T) void k_scan1(const int* __restrict__ deg, int* __restrict__ bsum, int n) {
    __shared__ int sd[SCAN_T];
    int b = blockIdx.x, t = threadIdx.x;
    int base = b * SCAN_E + t * 4;
    int s = 0;
#pragma unroll
    for (int j = 0; j < 4; ++j) s += (base + j < n) ? deg[base + j] : 0;
    sd[t] = s;
    __syncthreads();
    for (int off = SCAN_T / 2; off > 0; off >>= 1) {
        if (t < off) sd[t] += sd[t + off];
        __syncthreads();
    }
    if (t == 0) bsum[b] = sd[0];
}

__global__ void k_scan2(int* __restrict__ bsum, int nb, int* __restrict__ rowptr, int n) {
    if (threadIdx.x == 0 && blockIdx.x == 0) {
        int acc = 0;
        for (int b = 0; b < nb; ++b) { int v = bsum[b]; bsum[b] = acc; acc += v; }
        rowptr[n] = acc;
    }
}

__global__ __launch_bounds__(SCAN_T) void k_scan3(const int* __restrict__ deg, const int* __restrict__ bsum,
                                                  int* __restrict__ rowptr, int* __restrict__ cursor, int n) {
    __shared__ int sd[SCAN_T];
    int b = blockIdx.x, t = threadIdx.x;
    int base = b * SCAN_E + t * 4;
    int v[4]; int s = 0;
#pragma unroll
    for (int j = 0; j < 4; ++j) { v[j] = (base + j < n) ? deg[base + j] : 0; s += v[j]; }
    sd[t] = s;
    __syncthreads();
    for (int off = 1; off < SCAN_T; off <<= 1) {
        int x = (t >= off) ? sd[t - off] : 0;
        __syncthreads();
        sd[t] += x;
        __syncthreads();
    }
    int pre = bsum[b] + sd[t] - s;  // exclusive prefix for this thread's 4 elems
#pragma unroll
    for (int j = 0; j < 4; ++j) {
        if (base + j < n) { rowptr[base + j] = pre; cursor[base + j] = pre; pre += v[j]; }
    }
}

__global__ __launch_bounds__(256) void k_fill(const int* __restrict__ ei, int* __restrict__ cursor,
                                              int* __restrict__ csr, int E) {
    int e = blockIdx.x * 256 + threadIdx.x;
    if (e < E) {
        int s = ei[e];
        int d = ei[E + e];
        int p = atomicAdd(&cursor[d], 1);
        csr[p] = s;
    }
}

// ---------------- GEMM1: H1 = X @ W1   (M x 128) @ (128 x 128) ----------------
// block = 256 thr, 32 rows/block. W1 (64KB) + 32 X-rows (16KB) in LDS = 80KB -> 2 blocks/CU.
// thread tile 4 rows x 4 cols.

__global__ __launch_bounds__(256) void k_gemm1(const float* __restrict__ X, const float* __restrict__ W,
                                               float* __restrict__ H, int M) {
    __shared__ float ws[128 * 128];
    __shared__ float xs[32][128];
    int tid = threadIdx.x;
    for (int i = tid * 4; i < 128 * 128; i += 1024)
        *(float4*)&ws[i] = *(const float4*)&W[i];
    int row0 = blockIdx.x * 32;
    for (int i = tid; i < 32 * 32; i += 256) {
        int r = i >> 5, c4 = (i & 31) << 2;
        int gr = row0 + r;
        float4 v = (gr < M) ? *(const float4*)&X[(size_t)gr * 128 + c4] : make_float4(0.f, 0.f, 0.f, 0.f);
        *(float4*)&xs[r][c4] = v;
    }
    __syncthreads();
    int tx = tid & 31, ty = tid >> 5;
    int c0 = tx << 2;
    int r0 = ty << 2;
    float acc[4][4] = {};
#pragma unroll 8
    for (int k = 0; k < 128; ++k) {
        float4 wv = *(float4*)&ws[k * 128 + c0];
        float x0 = xs[r0 + 0][k], x1 = xs[r0 + 1][k], x2 = xs[r0 + 2][k], x3 = xs[r0 + 3][k];
        acc[0][0] += x0 * wv.x; acc[0][1] += x0 * wv.y; acc[0][2] += x0 * wv.z; acc[0][3] += x0 * wv.w;
        acc[1][0] += x1 * wv.x; acc[1][1] += x1 * wv.y; acc[1][2] += x1 * wv.z; acc[1][3] += x1 * wv.w;
        acc[2][0] += x2 * wv.x; acc[2][1] += x2 * wv.y; acc[2][2] += x2 * wv.z; acc[2][3] += x2 * wv.w;
        acc[3][0] += x3 * wv.x; acc[3][1] += x3 * wv.y; acc[3][2] += x3 * wv.z; acc[3][3] += x3 * wv.w;
    }
#pragma unroll
    for (int rr = 0; rr < 4; ++rr) {
        int gr = row0 + r0 + rr;
        if (gr < M) {
            float4 o = make_float4(acc[rr][0], acc[rr][1], acc[rr][2], acc[rr][3]);
            *(float4*)&H[(size_t)gr * 128 + c0] = o;
        }
    }
}

// ---------------- GEMM2: H2 = A1 @ W2   (M x 128) @ (128 x 40) ----------------
// block = 256 thr, 64 rows/block. W2 (20KB) + 64 rows (33KB, stride 132) -> 3 blocks/CU.
// thread tile 2 rows x 5 cols.

__global__ __launch_bounds__(256) void k_gemm2(const float* __restrict__ A, const float* __restrict__ W,
                                               float* __restrict__ H, int M) {
    __shared__ float ws[128 * 40];
    __shared__ float xs[64][132];
    int tid = threadIdx.x;
    for (int i = tid * 4; i < 128 * 40; i += 1024)
        *(float4*)&ws[i] = *(const float4*)&W[i];
    int row0 = blockIdx.x * 64;
    for (int i = tid; i < 64 * 32; i += 256) {
        int r = i >> 5, c4 = (i & 31) << 2;
        int gr = row0 + r;
        float4 v = (gr < M) ? *(const float4*)&A[(size_t)gr * 128 + c4] : make_float4(0.f, 0.f, 0.f, 0.f);
        *(float4*)&xs[r][c4] = v;
    }
    __syncthreads();
    int tx = tid & 7, ty = tid >> 3;
    int c0 = tx * 5;
    int r0 = ty * 2;
    float acc[2][5] = {};
#pragma unroll 8
    for (int k = 0; k < 128; ++k) {
        float x0 = xs[r0][k], x1 = xs[r0 + 1][k];
#pragma unroll
        for (int j = 0; j < 5; ++j) {
            float w = ws[k * 40 + c0 + j];
            acc[0][j] += x0 * w;
            acc[1][j] += x1 * w;
        }
    }
#pragma unroll
    for (int rr = 0; rr < 2; ++rr) {
        int gr = row0 + r0 + rr;
        if (gr < M) {
#pragma unroll
            for (int j = 0; j < 5; ++j) H[(size_t)gr * 40 + c0 + j] = acc[rr][j];
        }
    }
}

// ---------------- AGG1: A1 = relu( Ahat @ H1 + b1 ) ----------------
// one 64-lane wave per node, float2 per lane over 128 cols; pull via CSR (no float atomics).

__global__ __launch_bounds__(256) void k_agg1(const float* __restrict__ H1, const int* __restrict__ csr,
                                              const int* __restrict__ rowptr, const float* __restrict__ dinv,
                                              const float* __restrict__ b1, float* __restrict__ A1, int n) {
    int node = (int)((blockIdx.x * 256 + threadIdx.x) >> 6);
    int lane = threadIdx.x & 63;
    if (node >= n) return;
    float di = dinv[node];
    int c = lane * 2;
    float2 hv = *(const float2*)&H1[(size_t)node * 128 + c];
    float wself = di * di;
    float ax = wself * hv.x, ay = wself * hv.y;
    int e0 = rowptr[node], e1 = rowptr[node + 1];
    for (int e = e0; e < e1; ++e) {
        int s = csr[e];
        float w = dinv[s] * di;
        float2 h = *(const float2*)&H1[(size_t)s * 128 + c];
        ax += w * h.x; ay += w * h.y;
    }
    ax = fmaxf(ax + b1[c], 0.f);
    ay = fmaxf(ay + b1[c + 1], 0.f);
    float2 o; o.x = ax; o.y = ay;
    *(float2*)&A1[(size_t)node * 128 + c] = o;
}

// ---------------- AGG2 + bias + log_softmax -> out ----------------
// one wave per node; lanes 0..39 hold the 40 classes; shfl-xor reductions.

__global__ __launch_bounds__(256) void k_agg2(const float* __restrict__ H2, const int* __restrict__ csr,
                                              const int* __restrict__ rowptr, const float* __restrict__ dinv,
                                              const float* __restrict__ b2, float* __restrict__ out, int n) {
    int node = (int)((blockIdx.x * 256 + threadIdx.x) >> 6);
    int lane = threadIdx.x & 63;
    if (node >= n) return;
    bool act = lane < NCLS;
    float di = dinv[node];
    float acc = 0.f;
    if (act) acc = di * di * H2[(size_t)node * NCLS + lane];
    int e0 = rowptr[node], e1 = rowptr[node + 1];
    for (int e = e0; e < e1; ++e) {
        int s = csr[e];
        float w = dinv[s] * di;
        if (act) acc += w * H2[(size_t)s * NCLS + lane];
    }
    if (act) acc += b2[lane];
    float v = act ? acc : -INFINITY;
#pragma unroll
    for (int off = 32; off > 0; off >>= 1) v = fmaxf(v, __shfl_xor(v, off, 64));
    float m = v;
    float ex = act ? expf(acc - m) : 0.f;
#pragma unroll
    for (int off = 32; off > 0; off >>= 1) ex += __shfl_xor(ex, off, 64);
    float ls = logf(ex);
    if (act) out[(size_t)node * NCLS + lane] = acc - m - ls;
}

// ---------------- launch ----------------

extern "C" void kernel_launch(void* const* d_in, const int* in_sizes, int n_in,
                              void* d_out, int out_size, void* d_ws, size_t ws_size,
                              hipStream_t stream) {
    const float* X  = (const float*)d_in[0];
    const int*   EI = (const int*)d_in[1];
    const float* W1 = (const float*)d_in[2];
    const float* B1 = (const float*)d_in[3];
    const float* W2 = (const float*)d_in[4];
    const float* B2 = (const float*)d_in[5];
    float* OUT = (float*)d_out;

    const int N = in_sizes[0] / F_INN;   // 100000
    const int E = in_sizes[1] / 2;       // 1600000

    char* ws = (char*)d_ws;
    size_t off = 0;
    auto alloc = [&](size_t bytes) -> void* {
        off = (off + 255) & ~(size_t)255;
        void* p = ws + off;
        off += bytes;
        return p;
    };
    float* H1     = (float*)alloc((size_t)N * HIDD * 4);   // 51.2 MB
    float* A1     = (float*)alloc((size_t)N * HIDD * 4);   // 51.2 MB
    float* H2     = (float*)alloc((size_t)N * NCLS * 4);   // 16.0 MB
    int*   deg    = (int*)  alloc((size_t)N * 4);
    float* dinv   = (float*)alloc((size_t)N * 4);
    int*   rowptr = (int*)  alloc((size_t)(N + 1) * 4);
    int*   cursor = (int*)  alloc((size_t)N * 4);
    int*   bsum   = (int*)  alloc(4096);
    int*   csr    = (int*)  alloc((size_t)E * 4);          // 6.4 MB

    hipMemsetAsync(deg, 0, (size_t)N * 4, stream);

    int eb = (E + 255) / 256;
    int nb = (N + 255) / 256;
    int nsb = (N + SCAN_E - 1) / SCAN_E;

    k_deg  <<<eb,  256, 0, stream>>>(EI, deg, E);
    k_dinv <<<nb,  256, 0, stream>>>(deg, dinv, N);
    k_scan1<<<nsb, SCAN_T, 0, stream>>>(deg, bsum, N);
    k_scan2<<<1,   64, 0, stream>>>(bsum, nsb, rowptr, N);
    k_scan3<<<nsb, SCAN_T, 0, stream>>>(deg, bsum, rowptr, cursor, N);
    k_fill <<<eb,  256, 0, stream>>>(EI, cursor, csr, E);

    k_gemm1<<<(N + 31) / 32, 256, 0, stream>>>(X, W1, H1, N);
    k_agg1 <<<(N + 3) / 4, 256, 0, stream>>>(H1, csr, rowptr, dinv, B1, A1, N);
    k_gemm2<<<(N + 63) / 64, 256, 0, stream>>>(A1, W2, H2, N);
    k_agg2 <<<(N + 3) / 4, 256, 0, stream>>>(H2, csr, rowptr, dinv, B2, OUT, N);
}

// Round 3
// 599.802 us; speedup vs baseline: 1.2130x; 1.2130x over previous
//
#include <hip/hip_runtime.h>
#include <cstdint>
#include <cmath>

#define F_INN 128
#define HIDD  128
#define NCLS  40

typedef unsigned int u32;
typedef unsigned short u16;

static __device__ __forceinline__ float bflo(u32 u) { return __builtin_bit_cast(float, u << 16); }
static __device__ __forceinline__ float bfhi(u32 u) { return __builtin_bit_cast(float, u & 0xffff0000u); }
static __device__ __forceinline__ u16 f2bf(float f) {
    u32 u = __builtin_bit_cast(u32, f);
    return (u16)((u + 0x7fffu + ((u >> 16) & 1u)) >> 16);
}
static __device__ __forceinline__ u32 pack2(float a, float b) {
    return (u32)f2bf(a) | ((u32)f2bf(b) << 16);
}

// ---------------- degree / norm ----------------

__global__ __launch_bounds__(256) void k_deg(const int* __restrict__ ei, int* __restrict__ deg, int E) {
    int e = blockIdx.x * 256 + threadIdx.x;
    if (e < E) atomicAdd(&deg[ei[E + e]], 1);   // dst = ei[1][e]
}

__global__ __launch_bounds__(256) void k_dinv(const int* __restrict__ deg, float* __restrict__ dinv, int n) {
    int i = blockIdx.x * 256 + threadIdx.x;
    if (i < n) dinv[i] = rsqrtf((float)(deg[i] + 1));  // +1 self loop
}

// ---------------- exclusive scan (rowptr) ----------------

#define SCAN_T 256
#define SCAN_E 1024

__global__ __launch_bounds__(SCAN_T) void k_scan1(const int* __restrict__ deg, int* __restrict__ bsum, int n) {
    __shared__ int sd[SCAN_T];
    int b = blockIdx.x, t = threadIdx.x;
    int base = b * SCAN_E + t * 4;
    int s = 0;
#pragma unroll
    for (int j = 0; j < 4; ++j) s += (base + j < n) ? deg[base + j] : 0;
    sd[t] = s;
    __syncthreads();
    for (int off = SCAN_T / 2; off > 0; off >>= 1) {
        if (t < off) sd[t] += sd[t + off];
        __syncthreads();
    }
    if (t == 0) bsum[b] = sd[0];
}

__global__ void k_scan2(int* __restrict__ bsum, int nb, int* __restrict__ rowptr, int n) {
    if (threadIdx.x == 0 && blockIdx.x == 0) {
        int acc = 0;
        for (int b = 0; b < nb; ++b) { int v = bsum[b]; bsum[b] = acc; acc += v; }
        rowptr[n] = acc;
    }
}

__global__ __launch_bounds__(SCAN_T) void k_scan3(const int* __restrict__ deg, const int* __restrict__ bsum,
                                                  int* __restrict__ rowptr, int* __restrict__ cursor, int n) {
    __shared__ int sd[SCAN_T];
    int b = blockIdx.x, t = threadIdx.x;
    int base = b * SCAN_E + t * 4;
    int v[4]; int s = 0;
#pragma unroll
    for (int j = 0; j < 4; ++j) { v[j] = (base + j < n) ? deg[base + j] : 0; s += v[j]; }
    sd[t] = s;
    __syncthreads();
    for (int off = 1; off < SCAN_T; off <<= 1) {
        int x = (t >= off) ? sd[t - off] : 0;
        __syncthreads();
        sd[t] += x;
        __syncthreads();
    }
    int pre = bsum[b] + sd[t] - s;
#pragma unroll
    for (int j = 0; j < 4; ++j) {
        if (base + j < n) { rowptr[base + j] = pre; cursor[base + j] = pre; pre += v[j]; }
    }
}

__global__ __launch_bounds__(256) void k_fill(const int* __restrict__ ei, int* __restrict__ cursor,
                                              int* __restrict__ csr, int E) {
    int e = blockIdx.x * 256 + threadIdx.x;
    if (e < E) {
        int s = ei[e];
        int d = ei[E + e];
        int p = atomicAdd(&cursor[d], 1);
        csr[p] = s;
    }
}

// ---------------- GEMM1: H1 = bf16( X @ W1 )   (M x 128) @ (128 x 128) ----------------
// 32 rows/block; W1 64KB + xs 16KB LDS = 80KB -> 2 blocks/CU. k-loop vectorized x4.

__global__ __launch_bounds__(256) void k_gemm1(const float* __restrict__ X, const float* __restrict__ W,
                                               u32* __restrict__ H, int M) {
    __shared__ float ws[128 * 128];
    __shared__ float xs[32][128];
    int tid = threadIdx.x;
    for (int i = tid * 4; i < 128 * 128; i += 1024)
        *(float4*)&ws[i] = *(const float4*)&W[i];
    int row0 = blockIdx.x * 32;
    for (int i = tid; i < 32 * 32; i += 256) {
        int r = i >> 5, c4 = (i & 31) << 2;
        int gr = row0 + r;
        float4 v = (gr < M) ? *(const float4*)&X[(size_t)gr * 128 + c4] : make_float4(0.f, 0.f, 0.f, 0.f);
        *(float4*)&xs[r][c4] = v;
    }
    __syncthreads();
    int tx = tid & 31, ty = tid >> 5;
    int c0 = tx << 2;
    int r0 = ty << 2;
    float acc[4][4] = {};
#define ROWFMA(r, xr) { acc[r][0] += (xr) * wv.x; acc[r][1] += (xr) * wv.y; acc[r][2] += (xr) * wv.z; acc[r][3] += (xr) * wv.w; }
    for (int k0 = 0; k0 < 128; k0 += 4) {
        float4 xv0 = *(float4*)&xs[r0 + 0][k0];
        float4 xv1 = *(float4*)&xs[r0 + 1][k0];
        float4 xv2 = *(float4*)&xs[r0 + 2][k0];
        float4 xv3 = *(float4*)&xs[r0 + 3][k0];
#pragma unroll
        for (int kk = 0; kk < 4; ++kk) {
            float4 wv = *(float4*)&ws[(k0 + kk) * 128 + c0];
            float x0 = kk == 0 ? xv0.x : kk == 1 ? xv0.y : kk == 2 ? xv0.z : xv0.w;
            float x1 = kk == 0 ? xv1.x : kk == 1 ? xv1.y : kk == 2 ? xv1.z : xv1.w;
            float x2 = kk == 0 ? xv2.x : kk == 1 ? xv2.y : kk == 2 ? xv2.z : xv2.w;
            float x3 = kk == 0 ? xv3.x : kk == 1 ? xv3.y : kk == 2 ? xv3.z : xv3.w;
            ROWFMA(0, x0) ROWFMA(1, x1) ROWFMA(2, x2) ROWFMA(3, x3)
        }
    }
#undef ROWFMA
#pragma unroll
    for (int rr = 0; rr < 4; ++rr) {
        int gr = row0 + r0 + rr;
        if (gr < M) {
            // H row stride = 64 u32 (128 bf16); col offset c0/2 u32
            u32 w0 = pack2(acc[rr][0], acc[rr][1]);
            u32 w1 = pack2(acc[rr][2], acc[rr][3]);
            uint2 o; o.x = w0; o.y = w1;
            *(uint2*)&H[(size_t)gr * 64 + (c0 >> 1)] = o;
        }
    }
}

// ---------------- GEMM2: H2 = bf16( A1 @ W2 )   (M x 128) @ (128 x 40) ----------------
// H2 row stride = 32 u32 = 64 bf16 (cols 0..39 used). 64 rows/block.

__global__ __launch_bounds__(256) void k_gemm2(const u32* __restrict__ A, const float* __restrict__ W,
                                               u32* __restrict__ H, int M) {
    __shared__ float ws[128 * 40];
    __shared__ float xs[64][130];
    int tid = threadIdx.x;
    for (int i = tid * 4; i < 128 * 40; i += 1024)
        *(float4*)&ws[i] = *(const float4*)&W[i];
    int row0 = blockIdx.x * 64;
    for (int i = tid; i < 64 * 64; i += 256) {
        int r = i >> 6, cu = i & 63;
        int gr = row0 + r;
        u32 u = (gr < M) ? A[(size_t)gr * 64 + cu] : 0u;
        xs[r][cu * 2] = bflo(u);
        xs[r][cu * 2 + 1] = bfhi(u);
    }
    __syncthreads();
    int tx = tid & 7, ty = tid >> 3;
    int c0 = tx * 5;
    int r0 = ty * 2;
    float acc[2][5] = {};
#pragma unroll 8
    for (int k = 0; k < 128; ++k) {
        float x0 = xs[r0][k], x1 = xs[r0 + 1][k];
#pragma unroll
        for (int j = 0; j < 5; ++j) {
            float w = ws[k * 40 + c0 + j];
            acc[0][j] += x0 * w;
            acc[1][j] += x1 * w;
        }
    }
    u16* Hs = (u16*)H;
#pragma unroll
    for (int rr = 0; rr < 2; ++rr) {
        int gr = row0 + r0 + rr;
        if (gr < M) {
            // row stride 64 u16 — MUST match agg2's 32-u32 stride (R2 bug: was 128)
#pragma unroll
            for (int j = 0; j < 5; ++j) Hs[(size_t)gr * 64 + c0 + j] = f2bf(acc[rr][j]);
        }
    }
}

// ---------------- AGG1: A1 = bf16( relu( Ahat @ H1 + b1 ) ) ----------------
// one wave per node; lane reads packed uint (2 bf16); edge loop unrolled x2.

__global__ __launch_bounds__(256) void k_agg1(const u32* __restrict__ H1, const int* __restrict__ csr,
                                              const int* __restrict__ rowptr, const float* __restrict__ dinv,
                                              const float* __restrict__ b1, u32* __restrict__ A1, int n) {
    int node = (int)((blockIdx.x * 256 + threadIdx.x) >> 6);
    int lane = threadIdx.x & 63;
    if (node >= n) return;
    float di = dinv[node];
    u32 us = H1[(size_t)node * 64 + lane];
    float wself = di * di;
    float ax = wself * bflo(us), ay = wself * bfhi(us);
    int e0 = rowptr[node], e1 = rowptr[node + 1];
    int e = e0;
    for (; e + 1 < e1; e += 2) {
        int s0 = csr[e], s1 = csr[e + 1];
        float w0 = dinv[s0] * di, w1 = dinv[s1] * di;
        u32 u0 = H1[(size_t)s0 * 64 + lane];
        u32 u1 = H1[(size_t)s1 * 64 + lane];
        ax += w0 * bflo(u0) + w1 * bflo(u1);
        ay += w0 * bfhi(u0) + w1 * bfhi(u1);
    }
    if (e < e1) {
        int s0 = csr[e];
        float w0 = dinv[s0] * di;
        u32 u0 = H1[(size_t)s0 * 64 + lane];
        ax += w0 * bflo(u0);
        ay += w0 * bfhi(u0);
    }
    ax = fmaxf(ax + b1[lane * 2], 0.f);
    ay = fmaxf(ay + b1[lane * 2 + 1], 0.f);
    A1[(size_t)node * 64 + lane] = pack2(ax, ay);
}

// ---------------- AGG2 + bias + log_softmax -> out ----------------
// one wave per node; lanes 0..19 each own 2 classes (packed uint reads, H2 stride 32 u32).

__global__ __launch_bounds__(256) void k_agg2(const u32* __restrict__ H2, const int* __restrict__ csr,
                                              const int* __restrict__ rowptr, const float* __restrict__ dinv,
                                              const float* __restrict__ b2, float* __restrict__ out, int n) {
    int node = (int)((blockIdx.x * 256 + threadIdx.x) >> 6);
    int lane = threadIdx.x & 63;
    if (node >= n) return;
    bool act = lane < 20;
    int idx = act ? lane : 0;
    float di = dinv[node];
    u32 us = H2[(size_t)node * 32 + idx];
    float wself = di * di;
    float a0 = wself * bflo(us), a1 = wself * bfhi(us);
    int e0 = rowptr[node], e1 = rowptr[node + 1];
    int e = e0;
    for (; e + 1 < e1; e += 2) {
        int s0 = csr[e], s1 = csr[e + 1];
        float w0 = dinv[s0] * di, w1 = dinv[s1] * di;
        u32 u0 = H2[(size_t)s0 * 32 + idx];
        u32 u1 = H2[(size_t)s1 * 32 + idx];
        a0 += w0 * bflo(u0) + w1 * bflo(u1);
        a1 += w0 * bfhi(u0) + w1 * bfhi(u1);
    }
    if (e < e1) {
        int s0 = csr[e];
        float w0 = dinv[s0] * di;
        u32 u0 = H2[(size_t)s0 * 32 + idx];
        a0 += w0 * bflo(u0);
        a1 += w0 * bfhi(u0);
    }
    a0 += b2[idx * 2];
    a1 += b2[idx * 2 + 1];
    float v = act ? fmaxf(a0, a1) : -INFINITY;
#pragma unroll
    for (int off = 32; off > 0; off >>= 1) v = fmaxf(v, __shfl_xor(v, off, 64));
    float ex = act ? (expf(a0 - v) + expf(a1 - v)) : 0.f;
#pragma unroll
    for (int off = 32; off > 0; off >>= 1) ex += __shfl_xor(ex, off, 64);
    float ls = logf(ex);
    if (act) {
        float2 o; o.x = a0 - v - ls; o.y = a1 - v - ls;
        *(float2*)&out[(size_t)node * NCLS + lane * 2] = o;
    }
}

// ---------------- launch ----------------

extern "C" void kernel_launch(void* const* d_in, const int* in_sizes, int n_in,
                              void* d_out, int out_size, void* d_ws, size_t ws_size,
                              hipStream_t stream) {
    const float* X  = (const float*)d_in[0];
    const int*   EI = (const int*)d_in[1];
    const float* W1 = (const float*)d_in[2];
    const float* B1 = (const float*)d_in[3];
    const float* W2 = (const float*)d_in[4];
    const float* B2 = (const float*)d_in[5];
    float* OUT = (float*)d_out;

    const int N = in_sizes[0] / F_INN;   // 100000
    const int E = in_sizes[1] / 2;       // 1600000

    char* ws = (char*)d_ws;
    size_t off = 0;
    auto alloc = [&](size_t bytes) -> void* {
        off = (off + 255) & ~(size_t)255;
        void* p = ws + off;
        off += bytes;
        return p;
    };
    u32*   H1     = (u32*)  alloc((size_t)N * 64 * 4);   // 25.6 MB (bf16 x 128)
    u32*   A1     = (u32*)  alloc((size_t)N * 64 * 4);   // 25.6 MB
    u32*   H2     = (u32*)  alloc((size_t)N * 32 * 4);   // 12.8 MB (bf16 x 64, 40 used)
    int*   deg    = (int*)  alloc((size_t)N * 4);
    float* dinv   = (float*)alloc((size_t)N * 4);
    int*   rowptr = (int*)  alloc((size_t)(N + 1) * 4);
    int*   cursor = (int*)  alloc((size_t)N * 4);
    int*   bsum   = (int*)  alloc(4096);
    int*   csr    = (int*)  alloc((size_t)E * 4);        // 6.4 MB

    hipMemsetAsync(deg, 0, (size_t)N * 4, stream);

    int eb = (E + 255) / 256;
    int nb = (N + 255) / 256;
    int nsb = (N + SCAN_E - 1) / SCAN_E;

    k_deg  <<<eb,  256, 0, stream>>>(EI, deg, E);
    k_dinv <<<nb,  256, 0, stream>>>(deg, dinv, N);
    k_scan1<<<nsb, SCAN_T, 0, stream>>>(deg, bsum, N);
    k_scan2<<<1,   64, 0, stream>>>(bsum, nsb, rowptr, N);
    k_scan3<<<nsb, SCAN_T, 0, stream>>>(deg, bsum, rowptr, cursor, N);
    k_fill <<<eb,  256, 0, stream>>>(EI, cursor, csr, E);

    k_gemm1<<<(N + 31) / 32, 256, 0, stream>>>(X, W1, H1, N);
    k_agg1 <<<(N + 3) / 4, 256, 0, stream>>>(H1, csr, rowptr, dinv, B1, A1, N);
    k_gemm2<<<(N + 63) / 64, 256, 0, stream>>>(A1, W2, H2, N);
    k_agg2 <<<(N + 3) / 4, 256, 0, stream>>>(H2, csr, rowptr, dinv, B2, OUT, N);
}